// Round 2
// baseline (410.499 us; speedup 1.0000x reference)
//
#include <hip/hip_runtime.h>
#include <hip/hip_bf16.h>

// GATNE-T fused inference kernel — fp32 in/out (reference dtypes).
// Shapes: V=500000, T=4, D=32, E=128, A=32, B=8192, S=10.
// One block (128 threads = 2 waves) per batch element.

constexpr int TT = 4;    // edge types
constexpr int DD = 32;   // edge embedding size
constexpr int EE = 128;  // embedding size
constexpr int AA = 32;   // attention dim
constexpr int SS = 10;   // neighbor samples

__global__ __launch_bounds__(128) void gatne_fused(
    const int*   __restrict__ targets,      // [B]
    const int*   __restrict__ types,        // [B]
    const int*   __restrict__ neighbors,    // [B,T,S]
    const float* __restrict__ base_emb,     // [V,E]
    const float* __restrict__ nte,          // [V,T,D]
    const float* __restrict__ tw,           // [T,D,E]
    const float* __restrict__ tw1,          // [T,D,A]
    const float* __restrict__ tw2,          // [T,A]  (trailing dim 1 dropped)
    float*       __restrict__ out)          // [B,E]
{
    const int b    = blockIdx.x;
    const int tid  = threadIdx.x;          // 0..127
    const int t    = tid >> 5;             // 0..3 (edge type)
    const int lane = tid & 31;             // 0..31 (d or a index)

    __shared__ float s_agg[TT][DD];        // node_agg[t][d]
    __shared__ float s_scores[TT];
    __shared__ float s_natt[DD];
    __shared__ int   s_nb[TT * SS];
    __shared__ int   s_meta[2];            // {type, target}
    __shared__ float s_part[2];
    __shared__ float s_inv;

    if (tid == 0) s_meta[0] = types[b];
    if (tid == 1) s_meta[1] = targets[b];
    if (tid < TT * SS) s_nb[tid] = neighbors[b * (TT * SS) + tid];
    __syncthreads();

    const int ty = s_meta[0];
    const int tg = s_meta[1];

    // ---- 1) node_agg[t][d] = mean_s nte[nb[t][s]][t][d] ----
    // Each 32-lane group reads one contiguous 128B row per (t,s): coalesced.
    float acc = 0.f;
    #pragma unroll
    for (int s = 0; s < SS; ++s) {
        const int v = s_nb[t * SS + s];
        acc += nte[(long long)v * (TT * DD) + t * DD + lane];
    }
    s_agg[t][lane] = acc * 0.1f;
    __syncthreads();

    // ---- 2) u[t][a] = tanh(sum_d agg[t][d] * tw1[ty][d][a]) ; score[t] ----
    float ua = 0.f;
    #pragma unroll
    for (int d = 0; d < DD; ++d)
        ua += s_agg[t][d] * tw1[ty * (DD * AA) + d * AA + lane];
    ua = tanhf(ua);

    float p = ua * tw2[ty * AA + lane];
    // reduce over a within each 32-lane group (xor masks < 32 stay in-group)
    #pragma unroll
    for (int m = 16; m >= 1; m >>= 1)
        p += __shfl_xor(p, m, 64);
    if (lane == 0) s_scores[t] = p;
    __syncthreads();

    // ---- 3) softmax over T=4 (redundantly per thread; trivial) ----
    const float sc0 = s_scores[0], sc1 = s_scores[1];
    const float sc2 = s_scores[2], sc3 = s_scores[3];
    const float mx  = fmaxf(fmaxf(sc0, sc1), fmaxf(sc2, sc3));
    const float e0 = expf(sc0 - mx), e1 = expf(sc1 - mx);
    const float e2 = expf(sc2 - mx), e3 = expf(sc3 - mx);
    const float inv_sum = 1.f / (e0 + e1 + e2 + e3);

    // ---- 4) node_att[d] = sum_t att[t] * agg[t][d] ----
    if (tid < DD) {
        const float na = (e0 * s_agg[0][tid] + e1 * s_agg[1][tid] +
                          e2 * s_agg[2][tid] + e3 * s_agg[3][tid]) * inv_sum;
        s_natt[tid] = na;
    }
    __syncthreads();

    // ---- 5) proj[e] = sum_d natt[d] * tw[ty][d][e] ; add base; l2 norm ----
    float val = 0.f;
    #pragma unroll
    for (int d = 0; d < DD; ++d)
        val += s_natt[d] * tw[ty * (DD * EE) + d * EE + tid];
    val += base_emb[(long long)tg * EE + tid];

    float sq = val * val;
    #pragma unroll
    for (int m = 32; m >= 1; m >>= 1)
        sq += __shfl_xor(sq, m, 64);
    if ((tid & 63) == 0) s_part[tid >> 6] = sq;
    __syncthreads();
    if (tid == 0) s_inv = rsqrtf(fmaxf(s_part[0] + s_part[1], 1e-12f));
    __syncthreads();

    out[b * EE + tid] = val * s_inv;
}

extern "C" void kernel_launch(void* const* d_in, const int* in_sizes, int n_in,
                              void* d_out, int out_size, void* d_ws, size_t ws_size,
                              hipStream_t stream) {
    const int*   targets   = (const int*)d_in[0];
    const int*   types     = (const int*)d_in[1];
    const int*   neighbors = (const int*)d_in[2];
    const float* base_emb  = (const float*)d_in[3];
    const float* nte       = (const float*)d_in[4];
    const float* tw        = (const float*)d_in[5];
    const float* tw1       = (const float*)d_in[6];
    const float* tw2       = (const float*)d_in[7];
    float*       out       = (float*)d_out;

    const int B = in_sizes[0];   // 8192
    (void)n_in; (void)out_size; (void)d_ws; (void)ws_size;

    gatne_fused<<<B, 128, 0, stream>>>(targets, types, neighbors,
                                       base_emb, nte, tw, tw1, tw2, out);
}